// Round 1
// baseline (1494.666 us; speedup 1.0000x reference)
//
#include <hip/hip_runtime.h>
#include <hip/hip_bf16.h>

namespace {

constexpr int Nn = 64, Cc = 64, Tt = 300, Vv = 25, Kk = 3, KTt = 9;
constexpr int TT1 = 3;                 // K1 t-tile -> 100 tiles
constexpr int TW1 = TT1 * Vv;          // 75
constexpr int TT2 = 12;                // K2 t-tile -> 25 tiles
constexpr int WIN = TT2 + KTt - 1;     // 20
constexpr float EPSf = 1e-5f;

__device__ __forceinline__ float bf2f(unsigned short u) {
  union { unsigned int i; float f; } c; c.i = ((unsigned int)u) << 16; return c.f;
}
__device__ __forceinline__ unsigned short f2bu(float f) {
  union { float f; unsigned int i; } c; c.f = f;
  unsigned int r = c.i + 0x7fffu + ((c.i >> 16) & 1u);   // RNE
  return (unsigned short)(r >> 16);
}

// ---------------------------------------------------------------------------
// K1: fused GCN:  xa[k,ci][t,w] = sum_v x[n,ci,t,v] * A[n,k,v,w]
//                 z[c][t,w]     = sum_{k,ci} W[k*64+c,ci] * xa + bias-term
//                 z' = relu(bn1(z))  -> bf16 workspace
// grid (100, 64), block 256
// ---------------------------------------------------------------------------
__global__ __launch_bounds__(256) void k1_gcn(
    const float* __restrict__ x, const float* __restrict__ A,
    const float* __restrict__ Wc, const float* __restrict__ bc,
    const float* __restrict__ g1, const float* __restrict__ b1,
    const float* __restrict__ m1, const float* __restrict__ v1,
    unsigned short* __restrict__ zp)
{
  __shared__ float As[Kk * Vv * Vv];                 // 7500 B
  __shared__ float SA[Kk * Vv];                      // 300 B
  __shared__ unsigned short WT[Cc][Kk * Cc];         // [ci][o] bf16, 24576 B
  __shared__ unsigned short xa[Kk * Cc][80];         // bf16, 30720 B (padded 75->80)

  const int tid = threadIdx.x;
  const int tt  = blockIdx.x;          // 0..99
  const int n   = blockIdx.y;
  const int t0  = tt * TT1;

  const float* An = A + n * (Kk * Vv * Vv);
  for (int e = tid; e < Kk * Vv * Vv; e += 256) As[e] = An[e];
  // transpose conv_w into LDS (contiguous-in-o rows so stage-2 lane reads are contiguous)
  for (int e = tid; e < Cc * Kk * Cc; e += 256) {
    int ci = e / (Kk * Cc), o = e - ci * (Kk * Cc);
    WT[ci][o] = f2bu(Wc[o * Cc + ci]);
  }
  __syncthreads();

  // SA[k][w] = sum_v A[k][v][w]  (for folded conv-bias)
  for (int e = tid; e < Kk * Vv; e += 256) {
    int k = e / Vv, w = e - k * Vv;
    float s = 0.f;
    for (int v = 0; v < Vv; ++v) s += As[k * Vv * Vv + v * Vv + w];
    SA[e] = s;
  }
  // stage-1: build xa. 576 (r,t) rows, each computes 25 w's with vectorized A rows
  for (int e = tid; e < Kk * Cc * TT1; e += 256) {
    int r = e / TT1, tl = e - r * TT1;
    int k = r >> 6, ci = r & 63;
    const float* xrow = x + ((size_t)(n * Cc + ci) * Tt + (t0 + tl)) * Vv;
    const float* Ak = As + k * Vv * Vv;
    float acc[Vv];
    #pragma unroll
    for (int w = 0; w < Vv; ++w) acc[w] = 0.f;
    #pragma unroll
    for (int v = 0; v < Vv; ++v) {
      float xv = xrow[v];
      #pragma unroll
      for (int w = 0; w < Vv; ++w) acc[w] += xv * Ak[v * Vv + w];
    }
    #pragma unroll
    for (int w = 0; w < Vv; ++w) xa[r][tl * Vv + w] = f2bu(acc[w]);
  }
  __syncthreads();

  // stage-2: z[c][tw], 4 c's x 5 tw's per thread
  const int c_base = (tid >> 4) << 2;   // 0,4,...,60 (per 16-thread group)
  const int gq = tid & 15;              // tv fast across lanes -> coalesced stores
  float acc[4][5];
  float bcv[4][3];
  #pragma unroll
  for (int m = 0; m < 4; ++m)
    #pragma unroll
    for (int k = 0; k < 3; ++k) bcv[m][k] = bc[k * Cc + c_base + m];
  #pragma unroll
  for (int j = 0; j < 5; ++j) {
    int tw = gq + 16 * j;
    int w = tw % Vv;                    // safe even for tw>=75 (masked at store)
    #pragma unroll
    for (int m = 0; m < 4; ++m) {
      float s = 0.f;
      #pragma unroll
      for (int k = 0; k < 3; ++k) s += bcv[m][k] * SA[k * Vv + w];
      acc[m][j] = s;
    }
  }
  #pragma unroll 1
  for (int k = 0; k < 3; ++k) {
    #pragma unroll 1
    for (int ci = 0; ci < Cc; ++ci) {
      int r = (k << 6) + ci;
      const ushort4 wu = *(const ushort4*)&WT[ci][(k << 6) + c_base];
      float wv0 = bf2f(wu.x), wv1 = bf2f(wu.y), wv2 = bf2f(wu.z), wv3 = bf2f(wu.w);
      #pragma unroll
      for (int j = 0; j < 5; ++j) {
        float xv = bf2f(xa[r][gq + 16 * j]);
        acc[0][j] += wv0 * xv;
        acc[1][j] += wv1 * xv;
        acc[2][j] += wv2 * xv;
        acc[3][j] += wv3 * xv;
      }
    }
  }
  // bn1 + relu -> bf16 z'
  #pragma unroll
  for (int m = 0; m < 4; ++m) {
    int c = c_base + m;
    float inv = g1[c] * rsqrtf(v1[c] + EPSf);
    float add = b1[c] - m1[c] * inv;
    unsigned short* zrow = zp + ((size_t)(n * Cc + c) * Tt + t0) * Vv;
    #pragma unroll
    for (int j = 0; j < 5; ++j) {
      int tw = gq + 16 * j;
      if (tw < TW1) {
        float zz = fmaxf(acc[m][j] * inv + add, 0.f);
        zrow[tw] = f2bu(zz);
      }
    }
  }
}

// ---------------------------------------------------------------------------
// K2: fused TCN: h = tconv(z') + tb; out = relu(bn2(h) + x)
// grid (25, 64), block 256; 4 ci-phases of 16 channels each
// ---------------------------------------------------------------------------
__global__ __launch_bounds__(256) void k2_tcn(
    const unsigned short* __restrict__ zp,
    const float* __restrict__ twt, const float* __restrict__ tb,
    const float* __restrict__ g2, const float* __restrict__ b2,
    const float* __restrict__ m2, const float* __restrict__ v2,
    const float* __restrict__ x, float* __restrict__ out)
{
  __shared__ unsigned short zwin[16][504];        // 16 ci x (20t*25v), padded
  __shared__ unsigned short TWt[16 * KTt][Cc];    // [(ci,kt)][co] bf16

  const int tid = threadIdx.x;
  const int tt  = blockIdx.x;      // 0..24
  const int n   = blockIdx.y;
  const int t0  = tt * TT2;
  const int co_base = (tid >> 4) << 2;
  const int gq = tid & 15;

  float acc[4][19];
  #pragma unroll
  for (int m = 0; m < 4; ++m)
    #pragma unroll
    for (int j = 0; j < 19; ++j) acc[m][j] = 0.f;

  #pragma unroll 1
  for (int ph = 0; ph < 4; ++ph) {
    __syncthreads();
    // stage z' window (zero-padded at t edges)
    for (int e = tid; e < 16 * WIN * Vv; e += 256) {
      int cl = e / (WIN * Vv), rest = e - cl * (WIN * Vv);
      int flat = (t0 - 4) * Vv + rest;
      unsigned short val = 0;
      if (flat >= 0 && flat < Tt * Vv)
        val = zp[((size_t)(n * Cc + ph * 16 + cl) * Tt) * Vv + flat];
      zwin[cl][rest] = val;
    }
    // stage transposed weights for this ci-quarter
    for (int e = tid; e < 144 * Cc; e += 256) {
      int co = e & 63, rl = e >> 6;
      TWt[rl][co] = f2bu(twt[co * (Cc * KTt) + ph * 144 + rl]);
    }
    __syncthreads();

    #pragma unroll 1
    for (int cl = 0; cl < 16; ++cl) {
      #pragma unroll 1
      for (int kt = 0; kt < KTt; ++kt) {
        const ushort4 wu = *(const ushort4*)&TWt[cl * KTt + kt][co_base];
        float wv0 = bf2f(wu.x), wv1 = bf2f(wu.y), wv2 = bf2f(wu.z), wv3 = bf2f(wu.w);
        const unsigned short* zr = &zwin[cl][kt * Vv];
        #pragma unroll
        for (int j = 0; j < 19; ++j) {
          float zv = bf2f(zr[gq + 16 * j]);
          acc[0][j] += wv0 * zv;
          acc[1][j] += wv1 * zv;
          acc[2][j] += wv2 * zv;
          acc[3][j] += wv3 * zv;
        }
      }
    }
  }
  // epilogue: +tb, bn2, +x residual, relu  (coalesced 64B segments)
  #pragma unroll
  for (int m = 0; m < 4; ++m) {
    int c = co_base + m;
    float inv  = g2[c] * rsqrtf(v2[c] + EPSf);
    float addc = (b2[c] - m2[c] * inv) + tb[c] * inv;
    const float* xrow = x   + ((size_t)(n * Cc + c) * Tt + t0) * Vv;
    float*       orow = out + ((size_t)(n * Cc + c) * Tt + t0) * Vv;
    #pragma unroll
    for (int j = 0; j < 19; ++j) {
      int tv = gq + 16 * j;
      if (tv < TT2 * Vv) {
        float h = acc[m][j] * inv + addc + xrow[tv];
        orow[tv] = fmaxf(h, 0.f);
      }
    }
  }
}

// ---------------------------------------------------------------------------
// K3: copy A to output tail (tuple output: (out, A))
// ---------------------------------------------------------------------------
__global__ void k3_copyA(const float* __restrict__ A, float* __restrict__ outA) {
  int i = blockIdx.x * 256 + threadIdx.x;
  if (i < Nn * Kk * Vv * Vv) outA[i] = A[i];
}

} // namespace

extern "C" void kernel_launch(void* const* d_in, const int* in_sizes, int n_in,
                              void* d_out, int out_size, void* d_ws, size_t ws_size,
                              hipStream_t stream)
{
  const float* x  = (const float*)d_in[0];
  const float* A  = (const float*)d_in[1];
  const float* Wc = (const float*)d_in[2];
  const float* bc = (const float*)d_in[3];
  const float* g1 = (const float*)d_in[4];
  const float* b1 = (const float*)d_in[5];
  const float* m1 = (const float*)d_in[6];
  const float* v1 = (const float*)d_in[7];
  const float* tw = (const float*)d_in[8];
  const float* tb = (const float*)d_in[9];
  const float* g2 = (const float*)d_in[10];
  const float* b2 = (const float*)d_in[11];
  const float* m2 = (const float*)d_in[12];
  const float* v2 = (const float*)d_in[13];
  float* out = (float*)d_out;
  unsigned short* zp = (unsigned short*)d_ws;   // z' bf16, 61.44 MB

  dim3 blk(256);
  k1_gcn<<<dim3(Tt / TT1, Nn), blk, 0, stream>>>(x, A, Wc, bc, g1, b1, m1, v1, zp);
  k2_tcn<<<dim3(Tt / TT2, Nn), blk, 0, stream>>>(zp, tw, tb, g2, b2, m2, v2, x, out);
  k3_copyA<<<dim3((Nn * Kk * Vv * Vv + 255) / 256), blk, 0, stream>>>(
      A, out + (size_t)Nn * Cc * Tt * Vv);
}

// Round 2
// 269.355 us; speedup vs baseline: 5.5491x; 5.5491x over previous
//
#include <hip/hip_runtime.h>

typedef float f32x4 __attribute__((ext_vector_type(4)));
typedef short bf16x8 __attribute__((ext_vector_type(8)));
typedef unsigned short u16;

namespace {

constexpr int Nn = 64, Tt = 300, Vv = 25;
constexpr float EPSf = 1e-5f;

__device__ __forceinline__ u16 f2bu(float f) {
  union { float f; unsigned int i; } c; c.f = f;
  unsigned int r = c.i + 0x7fffu + ((c.i >> 16) & 1u);   // RNE
  return (u16)(r >> 16);
}

// ---------------------------------------------------------------------------
// prep: blocks 0..63 -> per-n AT (padded, transposed, bf16) + bias2d table
//       block 64     -> wT, w2T, folded BN coefficients
// ---------------------------------------------------------------------------
__global__ __launch_bounds__(256) void prep(
    const float* __restrict__ A, const float* __restrict__ Wc, const float* __restrict__ bc,
    const float* __restrict__ g1, const float* __restrict__ b1,
    const float* __restrict__ m1, const float* __restrict__ v1,
    const float* __restrict__ tcw, const float* __restrict__ tb,
    const float* __restrict__ g2, const float* __restrict__ b2,
    const float* __restrict__ m2, const float* __restrict__ v2,
    u16* __restrict__ atk, u16* __restrict__ wt, u16* __restrict__ w2t,
    float* __restrict__ invadd, float* __restrict__ bias2d)
{
  const int b = blockIdx.x, tid = threadIdx.x;
  if (b < 64) {
    __shared__ float Al[1875];
    __shared__ float SAl[75];
    const float* An = A + b * 1875;
    for (int e = tid; e < 1875; e += 256) Al[e] = An[e];
    __syncthreads();
    if (tid < 75) {
      int k = tid / 25, w = tid % 25;
      float s = 0.f;
      for (int v = 0; v < 25; ++v) s += Al[k * 625 + v * 25 + w];
      SAl[tid] = s;
    }
    __syncthreads();
    // AT[k][w(32)][v(32)] = A[n][k][v][w], zero-padded
    for (int e = tid; e < 3072; e += 256) {
      int k = e >> 10, r = e & 1023, w = r >> 5, v = r & 31;
      float val = (v < 25 && w < 25) ? Al[k * 625 + v * 25 + w] : 0.f;
      atk[b * 3072 + e] = f2bu(val);
    }
    // bias2d[n][c][w] = sum_k bc[k*64+c] * SA[k][w]
    for (int e = tid; e < 1600; e += 256) {
      int c = e / 25, w = e % 25;
      bias2d[b * 1600 + e] = bc[c] * SAl[w] + bc[64 + c] * SAl[25 + w] + bc[128 + c] * SAl[50 + w];
    }
  } else {
    // wT[c][r=k*64+ci] = conv_w[k*64+c][ci]
    for (int e = tid; e < 12288; e += 256) {
      int c = e / 192, r = e - c * 192, k = r >> 6, ci = r & 63;
      wt[e] = f2bu(Wc[(k * 64 + c) * 64 + ci]);
    }
    // w2T[kt][co][ci] = tconv_w[co][ci][kt]
    for (int e = tid; e < 36864; e += 256) {
      int kt = e >> 12, rest = e & 4095, co = rest >> 6, ci = rest & 63;
      w2t[e] = f2bu(tcw[(co * 64 + ci) * 9 + kt]);
    }
    if (tid < 64) {
      int c = tid;
      float i1 = g1[c] * rsqrtf(v1[c] + EPSf);
      float a1 = b1[c] - m1[c] * i1;
      float i2 = g2[c] * rsqrtf(v2[c] + EPSf);
      float a2 = b2[c] - m2[c] * i2 + tb[c] * i2;
      invadd[c] = i1; invadd[64 + c] = a1; invadd[128 + c] = i2; invadd[192 + c] = a2;
    }
  }
}

// ---------------------------------------------------------------------------
// K1: fused GCN via MFMA. grid (50, 64), 256 threads = 4 waves, 6-t tile.
// stage1: xaT[tw<150][r=k*64+ci]  (LDS, swizzled)   = sum_v x * A
// stage2: z'T[tv][c] (global bf16) = relu(bn1(wT . xaT + bias2d))
// ---------------------------------------------------------------------------
__global__ __launch_bounds__(256) void k1_gcn(
    const float* __restrict__ x, const u16* __restrict__ atk, const u16* __restrict__ wt,
    const float* __restrict__ invadd, const float* __restrict__ bias2d,
    u16* __restrict__ zT)
{
  __shared__ __align__(16) u16 xaT[160 * 192];
  __shared__ float bias_l[1600];

  const int tid = threadIdx.x;
  const int tt = blockIdx.x, n = blockIdx.y;
  const int t0 = tt * 6;
  const int w = tid >> 6, l = tid & 63, lq = l & 15, g = l >> 4;

  for (int e = tid; e < 1600; e += 256) bias_l[e] = bias2d[n * 1600 + e];
  for (int e = tid; e < 10 * 192; e += 256) xaT[150 * 192 + e] = 0;  // garbage tail rows -> 0

  // hoisted stage-1 B-frags: B[v][w] stored AT[w][v]
  bf16x8 Bf[3][2];
  #pragma unroll
  for (int k = 0; k < 3; ++k)
    #pragma unroll
    for (int nt = 0; nt < 2; ++nt)
      Bf[k][nt] = *(const bf16x8*)(atk + ((size_t)(n * 3 + k) * 32 + nt * 16 + lq) * 32 + g * 8);

  // ---- stage 1: 24 M-tiles (6 t x 4 ci-tiles), wave w takes mt = w+4i ----
  #pragma unroll 1
  for (int i = 0; i < 6; ++i) {
    const int mt = w + 4 * i;
    const int tl = mt >> 2, ci0 = (mt & 3) << 4;
    const float* xr = x + ((size_t)(n * 64 + ci0 + lq) * Tt + t0 + tl) * Vv;
    bf16x8 a;
    if (g < 3) {
      #pragma unroll
      for (int j = 0; j < 8; ++j) a[j] = (short)f2bu(xr[g * 8 + j]);
    } else {
      #pragma unroll
      for (int j = 0; j < 8; ++j) a[j] = 0;
      a[0] = (short)f2bu(xr[24]);
    }
    #pragma unroll
    for (int k = 0; k < 3; ++k)
      #pragma unroll
      for (int nt = 0; nt < 2; ++nt) {
        f32x4 acc = {0.f, 0.f, 0.f, 0.f};
        acc = __builtin_amdgcn_mfma_f32_16x16x32_bf16(a, Bf[k][nt], acc, 0, 0, 0);
        const int wcol = nt * 16 + lq;
        if (wcol < 25) {
          const int twl = tl * 25 + wcol;
          ushort4 s;
          s.x = f2bu(acc[0]); s.y = f2bu(acc[1]); s.z = f2bu(acc[2]); s.w = f2bu(acc[3]);
          const int byte = twl * 384 + ((k * 128 + ci0 * 2 + g * 8) ^ ((twl & 7) << 4));
          *(ushort4*)((char*)xaT + byte) = s;
        }
      }
  }
  __syncthreads();

  // ---- stage 2: D[c][tw] ; waves split the 10 tw-tiles {w, w+4, w+8} ----
  f32x4 acc2[3][4];
  #pragma unroll
  for (int ni = 0; ni < 3; ++ni)
    #pragma unroll
    for (int ct = 0; ct < 4; ++ct) acc2[ni][ct] = (f32x4){0.f, 0.f, 0.f, 0.f};
  const int nvalid = (w < 2) ? 3 : 2;

  #pragma unroll 1
  for (int kc = 0; kc < 6; ++kc) {
    bf16x8 Af[4];
    #pragma unroll
    for (int ct = 0; ct < 4; ++ct)
      Af[ct] = *(const bf16x8*)(wt + (ct * 16 + lq) * 192 + kc * 32 + g * 8);
    #pragma unroll
    for (int ni = 0; ni < 3; ++ni) {
      if (ni < nvalid) {
        const int row = (w + 4 * ni) * 16 + lq;
        const int byte = row * 384 + ((kc * 64 + g * 16) ^ ((row & 7) << 4));
        const bf16x8 Bv = *(const bf16x8*)((const char*)xaT + byte);
        #pragma unroll
        for (int ct = 0; ct < 4; ++ct)
          acc2[ni][ct] = __builtin_amdgcn_mfma_f32_16x16x32_bf16(Af[ct], Bv, acc2[ni][ct], 0, 0, 0);
      }
    }
  }

  #pragma unroll
  for (int ni = 0; ni < 3; ++ni) {
    if (ni < nvalid) {
      const int twl = (w + 4 * ni) * 16 + lq;
      if (twl < 150) {
        const int wcol = twl % 25;
        const int tvg = tt * 150 + twl;
        #pragma unroll
        for (int ct = 0; ct < 4; ++ct) {
          const int c0 = ct * 16 + g * 4;
          const f32x4 iv = *(const f32x4*)(invadd + c0);
          const f32x4 av = *(const f32x4*)(invadd + 64 + c0);
          ushort4 s;
          float z0 = (acc2[ni][ct][0] + bias_l[(c0 + 0) * 25 + wcol]) * iv[0] + av[0];
          float z1 = (acc2[ni][ct][1] + bias_l[(c0 + 1) * 25 + wcol]) * iv[1] + av[1];
          float z2 = (acc2[ni][ct][2] + bias_l[(c0 + 2) * 25 + wcol]) * iv[2] + av[2];
          float z3 = (acc2[ni][ct][3] + bias_l[(c0 + 3) * 25 + wcol]) * iv[3] + av[3];
          s.x = f2bu(fmaxf(z0, 0.f)); s.y = f2bu(fmaxf(z1, 0.f));
          s.z = f2bu(fmaxf(z2, 0.f)); s.w = f2bu(fmaxf(z3, 0.f));
          *(ushort4*)(zT + ((size_t)n * 7500 + tvg) * 64 + c0) = s;
        }
      }
    }
  }
}

// ---------------------------------------------------------------------------
// K2: fused TCN via MFMA. grid (25, 64), 256 threads = 4 waves, 12-t tile.
// window z'T rows [t0*25-100, +504) staged swizzled; K-loop kt(9) x kc(2).
// out = relu(bn2(conv) + x), coalesced float4.
// ---------------------------------------------------------------------------
__global__ __launch_bounds__(256) void k2_tcn(
    const u16* __restrict__ zT, const u16* __restrict__ w2t,
    const float* __restrict__ invadd, const float* __restrict__ x,
    float* __restrict__ out)
{
  __shared__ __align__(16) u16 win[504 * 64];

  const int tid = threadIdx.x;
  const int tt = blockIdx.x, n = blockIdx.y;
  const int t0 = tt * 12;
  const int w = tid >> 6, l = tid & 63, lq = l & 15, g = l >> 4;
  const int tvbase = t0 * 25 - 100;

  for (int f = tid; f < 504 * 8; f += 256) {
    const int lrow = f >> 3, c16 = f & 7;
    const int tv = tvbase + lrow;
    bf16x8 val = {0, 0, 0, 0, 0, 0, 0, 0};
    if (tv >= 0 && tv < 7500)
      val = *(const bf16x8*)(zT + ((size_t)n * 7500 + tv) * 64 + c16 * 8);
    const int byte = lrow * 128 + ((c16 * 16) ^ ((lrow & 7) << 4));
    *(bf16x8*)((char*)win + byte) = val;
  }
  __syncthreads();

  f32x4 acc[5][4];
  #pragma unroll
  for (int mi = 0; mi < 5; ++mi)
    #pragma unroll
    for (int nt = 0; nt < 4; ++nt) acc[mi][nt] = (f32x4){0.f, 0.f, 0.f, 0.f};
  const int nmt = (w < 3) ? 5 : 4;      // 19 M-tiles over 4 waves

  #pragma unroll 1
  for (int kt = 0; kt < 9; ++kt) {
    #pragma unroll
    for (int kc = 0; kc < 2; ++kc) {
      bf16x8 Bw[4];
      #pragma unroll
      for (int nt = 0; nt < 4; ++nt)
        Bw[nt] = *(const bf16x8*)(w2t + ((size_t)(kt * 64 + nt * 16 + lq)) * 64 + kc * 32 + g * 8);
      #pragma unroll
      for (int mi = 0; mi < 5; ++mi) {
        if (mi < nmt) {
          const int lrow = (w + 4 * mi) * 16 + lq + kt * 25;
          const int byte = lrow * 128 + ((kc * 64 + g * 16) ^ ((lrow & 7) << 4));
          const bf16x8 Av = *(const bf16x8*)((const char*)win + byte);
          #pragma unroll
          for (int nt = 0; nt < 4; ++nt)
            acc[mi][nt] = __builtin_amdgcn_mfma_f32_16x16x32_bf16(Av, Bw[nt], acc[mi][nt], 0, 0, 0);
        }
      }
    }
  }

  #pragma unroll
  for (int mi = 0; mi < 5; ++mi) {
    if (mi < nmt) {
      const int tvl0 = (w + 4 * mi) * 16 + g * 4;
      if (tvl0 < 300) {
        #pragma unroll
        for (int nt = 0; nt < 4; ++nt) {
          const int co = nt * 16 + lq;
          const float i2 = invadd[128 + co], a2 = invadd[192 + co];
          const size_t base = (size_t)(n * 64 + co) * 7500 + t0 * 25 + tvl0;
          const f32x4 xv = *(const f32x4*)(x + base);
          f32x4 o;
          #pragma unroll
          for (int r = 0; r < 4; ++r)
            o[r] = fmaxf(acc[mi][nt][r] * i2 + a2 + xv[r], 0.f);
          *(f32x4*)(out + base) = o;
        }
      }
    }
  }
}

__global__ void k3_copyA(const float* __restrict__ A, float* __restrict__ outA) {
  int i = blockIdx.x * 256 + threadIdx.x;
  if (i < 64 * 3 * 25 * 25) outA[i] = A[i];
}

} // namespace

extern "C" void kernel_launch(void* const* d_in, const int* in_sizes, int n_in,
                              void* d_out, int out_size, void* d_ws, size_t ws_size,
                              hipStream_t stream)
{
  const float* x  = (const float*)d_in[0];
  const float* A  = (const float*)d_in[1];
  const float* Wc = (const float*)d_in[2];
  const float* bc = (const float*)d_in[3];
  const float* g1 = (const float*)d_in[4];
  const float* b1 = (const float*)d_in[5];
  const float* m1 = (const float*)d_in[6];
  const float* v1 = (const float*)d_in[7];
  const float* tw = (const float*)d_in[8];
  const float* tb = (const float*)d_in[9];
  const float* g2 = (const float*)d_in[10];
  const float* b2 = (const float*)d_in[11];
  const float* m2 = (const float*)d_in[12];
  const float* v2 = (const float*)d_in[13];
  float* out = (float*)d_out;

  char* ws = (char*)d_ws;
  u16*   zT     = (u16*)(ws);                        // 61,440,000 B
  u16*   atk    = (u16*)(ws + 61440000);             //    393,216 B
  u16*   wt     = (u16*)(ws + 61833216);             //     24,576 B
  u16*   w2t    = (u16*)(ws + 61857792);             //     73,728 B
  float* invadd = (float*)(ws + 61931520);           //      1,024 B
  float* bias2d = (float*)(ws + 61932544);           //    409,600 B

  prep<<<dim3(65), dim3(256), 0, stream>>>(A, Wc, bc, g1, b1, m1, v1, tw, tb,
                                           g2, b2, m2, v2, atk, wt, w2t, invadd, bias2d);
  k1_gcn<<<dim3(50, 64), dim3(256), 0, stream>>>(x, atk, wt, invadd, bias2d, zT);
  k2_tcn<<<dim3(25, 64), dim3(256), 0, stream>>>(zT, w2t, invadd, x, out);
  k3_copyA<<<dim3((120000 + 255) / 256), dim3(256), 0, stream>>>(A, out + 30720000);
}